// Round 10
// baseline (279.787 us; speedup 1.0000x reference)
//
#include <hip/hip_runtime.h>
#include <math.h>

#define NN    100000
#define INF_  256
#define HID   128
#define OUTF  16
#define NE    1600000
#define BUK   256
#define NBUK  ((NN + BUK - 1) / BUK)      // 391
#define NB_F  128                          // fill blocks
#define EPB_F (NE / NB_F)                  // 12500
#define NB2   (NBUK * NB_F)                // 50048
#define SCAN_T 1024
#define SVPT  ((NB2 + SCAN_T - 1) / SCAN_T)  // 49
#define GNPB  64                           // gather nodes per block
#define GGRID ((NN + GNPB - 1) / GNPB)     // 1563
#define TSTR  132                          // LDS t stride (dwords, 16B-aligned rows)

typedef __attribute__((ext_vector_type(4))) float f32x4;
typedef __attribute__((ext_vector_type(8))) short bf16x8;

__device__ inline unsigned short f32_to_bf16(float f) {
  union { float f; unsigned int u; } v; v.f = f;
  unsigned int x = v.u;
  unsigned int r = x + 0x7fffu + ((x >> 16) & 1u);  // RNE
  return (unsigned short)(r >> 16);
}
__device__ inline float bf16lo_to_f32(unsigned int u) {
  union { unsigned int u; float f; } v; v.u = u << 16; return v.f;
}
__device__ inline float bf16hi_to_f32(unsigned int u) {
  union { unsigned int u; float f; } v; v.u = u & 0xffff0000u; return v.f;
}

// ---------------------------------------------------------------- per-block bucket histogram -> H[bucket][block]
__global__ __launch_bounds__(256) void k_hist2d(const int* __restrict__ dst,
                                                int* __restrict__ H) {
  __shared__ int lh[NBUK];
  const int t = threadIdx.x;
  for (int i = t; i < NBUK; i += 256) lh[i] = 0;
  __syncthreads();
  const int beg = blockIdx.x * EPB_F;
  for (int i = beg + t; i < beg + EPB_F; i += 256) atomicAdd(&lh[dst[i] >> 8], 1);
  __syncthreads();
  for (int i = t; i < NBUK; i += 256) H[i * NB_F + blockIdx.x] = lh[i];
}

// ---------------------------------------------------------------- single-block exclusive scan of H -> base (NB2+1)
__global__ __launch_bounds__(SCAN_T) void k_scan(const int* __restrict__ H,
                                                 int* __restrict__ base) {
  __shared__ int sh[SCAN_T];
  const int t = threadIdx.x;
  int v[SVPT];
  int s = 0;
#pragma unroll
  for (int j = 0; j < SVPT; ++j) {
    const int idx = t * SVPT + j;
    v[j] = (idx < NB2) ? H[idx] : 0;
    s += v[j];
  }
  sh[t] = s;
  __syncthreads();
  for (int off = 1; off < SCAN_T; off <<= 1) {
    int tmp = (t >= off) ? sh[t - off] : 0;
    __syncthreads();
    sh[t] += tmp;
    __syncthreads();
  }
  int run = (t > 0) ? sh[t - 1] : 0;
#pragma unroll
  for (int j = 0; j < SVPT; ++j) {
    const int idx = t * SVPT + j;
    if (idx < NB2) base[idx] = run;
    run += v[j];
  }
  if (t == SCAN_T - 1) base[NB2] = run;  // == NE
}

// ---------------------------------------------------------------- direct fill: block-owned ranges, no global atomics
__global__ __launch_bounds__(256) void k_fillb(const int* __restrict__ src,
                                               const int* __restrict__ dst,
                                               const int* __restrict__ base,
                                               unsigned int* __restrict__ binned) {
  __shared__ int lbase[NBUK];
  __shared__ int lcnt[NBUK];
  const int t = threadIdx.x;
  for (int i = t; i < NBUK; i += 256) {
    lbase[i] = base[i * NB_F + blockIdx.x];
    lcnt[i] = 0;
  }
  __syncthreads();
  const int beg = blockIdx.x * EPB_F;
#pragma unroll 4
  for (int i = beg + t; i < beg + EPB_F; i += 256) {
    const int d = dst[i];
    const int b = d >> 8;
    const unsigned w = ((unsigned)src[i] << 8) | (unsigned)(d & 255);
    const int pos = atomicAdd(&lcnt[b], 1);
    binned[lbase[b] + pos] = w;
  }
}

// ---------------------------------------------------------------- per-bucket: hist -> rowptr/dinv, then csr scatter (L2-local)
__global__ __launch_bounds__(256) void k_csr(const unsigned int* __restrict__ binned,
                                             const int* __restrict__ base,
                                             int* __restrict__ rowptr,
                                             float* __restrict__ dinv,
                                             int* __restrict__ csr) {
  __shared__ int hist[BUK];
  __shared__ int sh[256];
  __shared__ int lcur[BUK];
  const int b = blockIdx.x, t = threadIdx.x;
  hist[t] = 0;
  __syncthreads();
  const int e0 = base[b * NB_F], e1 = base[(b + 1) * NB_F];
  for (int i = e0 + t; i < e1; i += 256) atomicAdd(&hist[binned[i] & 255u], 1);
  __syncthreads();
  const int hv = hist[t];
  sh[t] = hv;
  __syncthreads();
  for (int off = 1; off < 256; off <<= 1) {
    int tmp = (t >= off) ? sh[t - off] : 0;
    __syncthreads();
    sh[t] += tmp;
    __syncthreads();
  }
  const int excl = sh[t] - hv;
  lcur[t] = excl;
  const int nid = b * BUK + t;
  if (nid < NN) {
    rowptr[nid] = e0 + excl;
    dinv[nid] = rsqrtf((float)(hv + 1));
  }
  if (b == NBUK - 1 && t == 0) rowptr[NN] = e1;  // == NE
  __syncthreads();
  for (int i = e0 + t; i < e1; i += 256) {
    const unsigned w = binned[i];
    const int pos = atomicAdd(&lcur[w & 255u], 1);
    csr[e0 + pos] = (int)(w >> 8);
  }
}

// ---------------------------------------------------------------- W prep (bf16, transposed, pre-swizzled 16B chunks)
__global__ __launch_bounds__(256) void k_wprep(const float* __restrict__ W,
                                               unsigned short* __restrict__ WTs) {
  const int i = blockIdx.x * 256 + threadIdx.x;
  if (i >= INF_ * HID) return;
  const int k = i >> 7, n = i & 127;
  const int s = k >> 5, c = (k >> 3) & 3, j = k & 7;
  const int chunk = s * 512 + n * 4 + (c ^ (n & 3));
  WTs[chunk * 8 + j] = f32_to_bf16(W[i]);
}

// ---------------------------------------------------------------- MFMA GEMM: h2b = bf16( (x @ Wc) * dinv[row] )
__global__ __launch_bounds__(256) void k_gemm(const float* __restrict__ x,
                                              const unsigned short* __restrict__ WTs,
                                              const float* __restrict__ dinv,
                                              unsigned short* __restrict__ h2b) {
  __shared__ unsigned short xs[128 * 32];
  __shared__ unsigned short ws[128 * 32];
  const int tid = threadIdx.x;
  const int wave = tid >> 6, lane = tid & 63;
  const int l15 = lane & 15, l4 = lane >> 4;
  const int row0 = blockIdx.x * 128;

  f32x4 acc[2][8];
#pragma unroll
  for (int rb = 0; rb < 2; ++rb)
#pragma unroll
    for (int n = 0; n < 8; ++n) { acc[rb][n].x = 0.f; acc[rb][n].y = 0.f; acc[rb][n].z = 0.f; acc[rb][n].w = 0.f; }

  for (int s = 0; s < 8; ++s) {
#pragma unroll
    for (int p = 0; p < 2; ++p) {
      const int c = tid + p * 256;
      const int row = c >> 2, kc = c & 3;
      const int grow = row0 + row;
      unsigned short tmp[8];
      if (grow < NN) {
        const float4 v0 = *(const float4*)&x[(size_t)grow * INF_ + s * 32 + kc * 8];
        const float4 v1 = *(const float4*)&x[(size_t)grow * INF_ + s * 32 + kc * 8 + 4];
        tmp[0] = f32_to_bf16(v0.x); tmp[1] = f32_to_bf16(v0.y);
        tmp[2] = f32_to_bf16(v0.z); tmp[3] = f32_to_bf16(v0.w);
        tmp[4] = f32_to_bf16(v1.x); tmp[5] = f32_to_bf16(v1.y);
        tmp[6] = f32_to_bf16(v1.z); tmp[7] = f32_to_bf16(v1.w);
      } else {
#pragma unroll
        for (int j = 0; j < 8; ++j) tmp[j] = 0;
      }
      const int phys = kc ^ (row & 3);
      *(bf16x8*)&xs[(row * 4 + phys) * 8] = *(bf16x8*)tmp;
    }
#pragma unroll
    for (int p = 0; p < 2; ++p) {
      const int c = tid + p * 256;
      *(bf16x8*)&ws[c * 8] = *(const bf16x8*)&WTs[(s * 512 + c) * 8];
    }
    __syncthreads();
    bf16x8 af[2];
#pragma unroll
    for (int rb = 0; rb < 2; ++rb) {
      const int row = wave * 32 + rb * 16 + l15;
      af[rb] = *(const bf16x8*)&xs[(row * 4 + (l4 ^ (row & 3))) * 8];
    }
#pragma unroll
    for (int n = 0; n < 8; ++n) {
      const int col = n * 16 + l15;
      const bf16x8 bf = *(const bf16x8*)&ws[(col * 4 + (l4 ^ (col & 3))) * 8];
      acc[0][n] = __builtin_amdgcn_mfma_f32_16x16x32_bf16(af[0], bf, acc[0][n], 0, 0, 0);
      acc[1][n] = __builtin_amdgcn_mfma_f32_16x16x32_bf16(af[1], bf, acc[1][n], 0, 0, 0);
    }
    __syncthreads();
  }
#pragma unroll
  for (int rb = 0; rb < 2; ++rb) {
#pragma unroll
    for (int r = 0; r < 4; ++r) {
      const int rowg = row0 + wave * 32 + rb * 16 + l4 * 4 + r;
      if (rowg < NN) {
        const float dv = dinv[rowg];
#pragma unroll
        for (int n = 0; n < 8; ++n)
          h2b[(size_t)rowg * HID + n * 16 + l15] = f32_to_bf16(acc[rb][n][r] * dv);
      }
    }
  }
}

// ---------------------------------------------------------------- bf16 -> fp8 e4m3 neighbor cache (h8)
__global__ __launch_bounds__(256) void k_tofp8(const unsigned int* __restrict__ h2u,
                                               unsigned int* __restrict__ h8) {
  const int i = blockIdx.x * 256 + threadIdx.x;  // i < NN*HID/16 = 800000
  const uint4 a = *(const uint4*)&h2u[(size_t)i * 8];
  const uint4 b = *(const uint4*)&h2u[(size_t)i * 8 + 4];
  int w0 = 0, w1 = 0, w2 = 0, w3 = 0;
  w0 = __builtin_amdgcn_cvt_pk_fp8_f32(bf16lo_to_f32(a.x), bf16hi_to_f32(a.x), w0, false);
  w0 = __builtin_amdgcn_cvt_pk_fp8_f32(bf16lo_to_f32(a.y), bf16hi_to_f32(a.y), w0, true);
  w1 = __builtin_amdgcn_cvt_pk_fp8_f32(bf16lo_to_f32(a.z), bf16hi_to_f32(a.z), w1, false);
  w1 = __builtin_amdgcn_cvt_pk_fp8_f32(bf16lo_to_f32(a.w), bf16hi_to_f32(a.w), w1, true);
  w2 = __builtin_amdgcn_cvt_pk_fp8_f32(bf16lo_to_f32(b.x), bf16hi_to_f32(b.x), w2, false);
  w2 = __builtin_amdgcn_cvt_pk_fp8_f32(bf16lo_to_f32(b.y), bf16hi_to_f32(b.y), w2, true);
  w3 = __builtin_amdgcn_cvt_pk_fp8_f32(bf16lo_to_f32(b.z), bf16hi_to_f32(b.z), w3, false);
  w3 = __builtin_amdgcn_cvt_pk_fp8_f32(bf16lo_to_f32(b.w), bf16hi_to_f32(b.w), w3, true);
  uint4 o; o.x = (unsigned)w0; o.y = (unsigned)w1; o.z = (unsigned)w2; o.w = (unsigned)w3;
  *(uint4*)&h8[(size_t)i * 4] = o;
}

// ---------------------------------------------------------------- gather + finalize, two-phase block design
// phase 1: wave handles 4 nodes concurrently (16-lane group per node); lane m owns ch 8m..8m+7
// phase 2: 4 lanes per node compute 4 logits each from LDS t + LDS Wl
__global__ __launch_bounds__(256) void k_gather(const int* __restrict__ rowptr,
                                                const int* __restrict__ csr,
                                                const unsigned int* __restrict__ h8,
                                                const unsigned int* __restrict__ h2u,
                                                const float* __restrict__ dinv,
                                                const float* __restrict__ bc,
                                                const float* __restrict__ Wl,
                                                const float* __restrict__ bl,
                                                float* __restrict__ out) {
  __shared__ float ldsT[GNPB * TSTR];   // 33 KB
  __shared__ float ldsW[HID * OUTF];    // 8 KB
  const int tid = threadIdx.x;
  const int wid = tid >> 6, lane = tid & 63;
  const int eg = lane >> 4, m = lane & 15;
  const int v0 = blockIdx.x * GNPB;

  // preload Wl into LDS
  {
    const float4* Wg = (const float4*)Wl;
    float4* Ws = (float4*)ldsW;
#pragma unroll
    for (int i = 0; i < HID * OUTF / 4 / 256; ++i) Ws[i * 256 + tid] = Wg[i * 256 + tid];
  }

  const uint2* h8p = (const uint2*)h8;
  const float4 bca = *(const float4*)&bc[8 * m];
  const float4 bcb = *(const float4*)&bc[8 * m + 4];

  // ---- phase 1: gather
  for (int r = 0; r < 4; ++r) {
    const int vloc = wid * 16 + r * 4 + eg;
    const int v = v0 + vloc;
    int rp = 0, re = 0;
    if (v < NN) { rp = rowptr[v]; re = rowptr[v + 1]; }
    float acc[8];
#pragma unroll
    for (int q = 0; q < 8; ++q) acc[q] = 0.f;

    for (int base = 0;; base += 16) {
      if (!__any(rp + base < re)) break;
      const int idx = rp + base + m;
      const int csrv = (idx < re) ? csr[idx] : -1;
#pragma unroll
      for (int e = 0; e < 16; ++e) {
        const int src = __shfl(csrv, eg * 16 + e);
        if (src >= 0) {
          const uint2 u = h8p[(size_t)src * 16 + m];
          acc[0] += __builtin_amdgcn_cvt_f32_fp8(u.x, 0);
          acc[1] += __builtin_amdgcn_cvt_f32_fp8(u.x, 1);
          acc[2] += __builtin_amdgcn_cvt_f32_fp8(u.x, 2);
          acc[3] += __builtin_amdgcn_cvt_f32_fp8(u.x, 3);
          acc[4] += __builtin_amdgcn_cvt_f32_fp8(u.y, 0);
          acc[5] += __builtin_amdgcn_cvt_f32_fp8(u.y, 1);
          acc[6] += __builtin_amdgcn_cvt_f32_fp8(u.y, 2);
          acc[7] += __builtin_amdgcn_cvt_f32_fp8(u.y, 3);
        }
      }
    }
    if (v < NN) {
      const float dv = dinv[v];
      const uint4 su = *(const uint4*)&h2u[((size_t)v << 6) + 4 * m];
      float4 ta, tb;
      ta.x = fmaxf(fmaf(dv, acc[0] + bf16lo_to_f32(su.x), bca.x), 0.f);
      ta.y = fmaxf(fmaf(dv, acc[1] + bf16hi_to_f32(su.x), bca.y), 0.f);
      ta.z = fmaxf(fmaf(dv, acc[2] + bf16lo_to_f32(su.y), bca.z), 0.f);
      ta.w = fmaxf(fmaf(dv, acc[3] + bf16hi_to_f32(su.y), bca.w), 0.f);
      tb.x = fmaxf(fmaf(dv, acc[4] + bf16lo_to_f32(su.z), bcb.x), 0.f);
      tb.y = fmaxf(fmaf(dv, acc[5] + bf16hi_to_f32(su.z), bcb.y), 0.f);
      tb.z = fmaxf(fmaf(dv, acc[6] + bf16lo_to_f32(su.w), bcb.z), 0.f);
      tb.w = fmaxf(fmaf(dv, acc[7] + bf16hi_to_f32(su.w), bcb.w), 0.f);
      *(float4*)&ldsT[vloc * TSTR + 8 * m] = ta;
      *(float4*)&ldsT[vloc * TSTR + 8 * m + 4] = tb;
    }
  }
  __syncthreads();

  // ---- phase 2: finalize (4 lanes per node, 4 outputs per lane)
  const int nloc = wid * 16 + (lane >> 2);
  const int q = lane & 3;
  const int v = v0 + nloc;
  const float* tp = &ldsT[nloc * TSTR];
  float a0 = 0.f, a1 = 0.f, a2 = 0.f, a3 = 0.f;
#pragma unroll 8
  for (int c = 0; c < HID; ++c) {
    const float tc = tp[c];
    const float4 w4 = *(const float4*)&ldsW[c * OUTF + 4 * q];
    a0 = fmaf(tc, w4.x, a0);
    a1 = fmaf(tc, w4.y, a1);
    a2 = fmaf(tc, w4.z, a2);
    a3 = fmaf(tc, w4.w, a3);
  }
  const float4 bl4 = *(const float4*)&bl[4 * q];
  a0 += bl4.x; a1 += bl4.y; a2 += bl4.z; a3 += bl4.w;
  float mx = fmaxf(fmaxf(a0, a1), fmaxf(a2, a3));
  mx = fmaxf(mx, __shfl_xor(mx, 1));
  mx = fmaxf(mx, __shfl_xor(mx, 2));
  float se = expf(a0 - mx) + expf(a1 - mx) + expf(a2 - mx) + expf(a3 - mx);
  se += __shfl_xor(se, 1);
  se += __shfl_xor(se, 2);
  const float lse = mx + logf(se);
  if (v < NN) {
    float4 o4;
    o4.x = a0 - lse; o4.y = a1 - lse; o4.z = a2 - lse; o4.w = a3 - lse;
    *(float4*)&out[(size_t)v * OUTF + 4 * q] = o4;
  }
}

// ---------------------------------------------------------------- launch
extern "C" void kernel_launch(void* const* d_in, const int* in_sizes, int n_in,
                              void* d_out, int out_size, void* d_ws, size_t ws_size,
                              hipStream_t stream) {
  const float* x  = (const float*)d_in[0];
  const int*   ei = (const int*)d_in[1];
  const float* Wc = (const float*)d_in[2];
  const float* bc = (const float*)d_in[3];
  const float* Wl = (const float*)d_in[4];
  const float* bl = (const float*)d_in[5];
  float* out = (float*)d_out;

  unsigned short* h2b = (unsigned short*)d_ws;            // 25.6 MB
  unsigned short* WTs = h2b + (size_t)NN * HID;           // 64 KB
  float* dinv   = (float*)(WTs + (size_t)INF_ * HID);     // NN f32
  int*   rowptr = (int*)(dinv + NN);                      // NN+1
  int*   H      = rowptr + NN + 1;                        // NB2
  int*   base   = H + NB2;                                // NB2+1
  unsigned int* binned = (unsigned int*)(base + NB2 + 1); // NE
  int*   csr    = (int*)(binned + NE);                    // NE
  unsigned int* h8 = (unsigned int*)(csr + NE);           // NN*HID fp8 = 12.8 MB

  const int* srcv = ei;
  const int* dstv = ei + NE;

  k_hist2d<<<NB_F, 256, 0, stream>>>(dstv, H);
  k_scan<<<1, SCAN_T, 0, stream>>>(H, base);
  k_fillb<<<NB_F, 256, 0, stream>>>(srcv, dstv, base, binned);
  k_csr<<<NBUK, 256, 0, stream>>>(binned, base, rowptr, dinv, csr);
  k_wprep<<<(INF_ * HID + 255) / 256, 256, 0, stream>>>(Wc, WTs);
  k_gemm<<<(NN + 127) / 128, 256, 0, stream>>>(x, WTs, dinv, h2b);
  k_tofp8<<<(NN * HID / 16 + 255) / 256, 256, 0, stream>>>((const unsigned int*)h2b, h8);
  k_gather<<<GGRID, 256, 0, stream>>>(rowptr, csr, h8, (const unsigned int*)h2b,
                                      dinv, bc, Wl, bl, out);
}

// Round 12
// 249.544 us; speedup vs baseline: 1.1212x; 1.1212x over previous
//
#include <hip/hip_runtime.h>
#include <math.h>

#define NN    100000
#define INF_  256
#define HID   128
#define OUTF  16
#define NE    1600000
#define BUK   256
#define NBUK  ((NN + BUK - 1) / BUK)      // 391
#define NB_F  128                          // fill blocks
#define EPB_F (NE / NB_F)                  // 12500
#define NB2   (NBUK * NB_F)                // 50048
#define SCAN_T 1024
#define SVPT  ((NB2 + SCAN_T - 1) / SCAN_T)  // 49
#define GBLK  3125
#define NPW   8                            // nodes per wave (3125*4*8 = 100000)

typedef __attribute__((ext_vector_type(4))) float f32x4;
typedef __attribute__((ext_vector_type(8))) short bf16x8;

__device__ inline unsigned short f32_to_bf16(float f) {
  union { float f; unsigned int u; } v; v.f = f;
  unsigned int x = v.u;
  unsigned int r = x + 0x7fffu + ((x >> 16) & 1u);  // RNE
  return (unsigned short)(r >> 16);
}
__device__ inline float bf16lo_to_f32(unsigned int u) {
  union { unsigned int u; float f; } v; v.u = u << 16; return v.f;
}
__device__ inline float bf16hi_to_f32(unsigned int u) {
  union { unsigned int u; float f; } v; v.u = u & 0xffff0000u; return v.f;
}

// accumulate 8 fp8 channels from uint2 u into acc[0..7] (literal selectors required)
#define ACC_FP8(u, acc) do { \
  acc[0] += __builtin_amdgcn_cvt_f32_fp8((u).x, 0); \
  acc[1] += __builtin_amdgcn_cvt_f32_fp8((u).x, 1); \
  acc[2] += __builtin_amdgcn_cvt_f32_fp8((u).x, 2); \
  acc[3] += __builtin_amdgcn_cvt_f32_fp8((u).x, 3); \
  acc[4] += __builtin_amdgcn_cvt_f32_fp8((u).y, 0); \
  acc[5] += __builtin_amdgcn_cvt_f32_fp8((u).y, 1); \
  acc[6] += __builtin_amdgcn_cvt_f32_fp8((u).y, 2); \
  acc[7] += __builtin_amdgcn_cvt_f32_fp8((u).y, 3); \
} while (0)

// ---------------------------------------------------------------- per-block bucket histogram -> H[bucket][block]
__global__ __launch_bounds__(256) void k_hist2d(const int* __restrict__ dst,
                                                int* __restrict__ H) {
  __shared__ int lh[NBUK];
  const int t = threadIdx.x;
  for (int i = t; i < NBUK; i += 256) lh[i] = 0;
  __syncthreads();
  const int beg = blockIdx.x * EPB_F;
  for (int i = beg + t; i < beg + EPB_F; i += 256) atomicAdd(&lh[dst[i] >> 8], 1);
  __syncthreads();
  for (int i = t; i < NBUK; i += 256) H[i * NB_F + blockIdx.x] = lh[i];
}

// ---------------------------------------------------------------- single-block exclusive scan of H -> base (NB2+1)
__global__ __launch_bounds__(SCAN_T) void k_scan(const int* __restrict__ H,
                                                 int* __restrict__ base) {
  __shared__ int sh[SCAN_T];
  const int t = threadIdx.x;
  int v[SVPT];
  int s = 0;
#pragma unroll
  for (int j = 0; j < SVPT; ++j) {
    const int idx = t * SVPT + j;
    v[j] = (idx < NB2) ? H[idx] : 0;
    s += v[j];
  }
  sh[t] = s;
  __syncthreads();
  for (int off = 1; off < SCAN_T; off <<= 1) {
    int tmp = (t >= off) ? sh[t - off] : 0;
    __syncthreads();
    sh[t] += tmp;
    __syncthreads();
  }
  int run = (t > 0) ? sh[t - 1] : 0;
#pragma unroll
  for (int j = 0; j < SVPT; ++j) {
    const int idx = t * SVPT + j;
    if (idx < NB2) base[idx] = run;
    run += v[j];
  }
  if (t == SCAN_T - 1) base[NB2] = run;  // == NE
}

// ---------------------------------------------------------------- direct fill: block-owned ranges, no global atomics
__global__ __launch_bounds__(256) void k_fillb(const int* __restrict__ src,
                                               const int* __restrict__ dst,
                                               const int* __restrict__ base,
                                               unsigned int* __restrict__ binned) {
  __shared__ int lbase[NBUK];
  __shared__ int lcnt[NBUK];
  const int t = threadIdx.x;
  for (int i = t; i < NBUK; i += 256) {
    lbase[i] = base[i * NB_F + blockIdx.x];
    lcnt[i] = 0;
  }
  __syncthreads();
  const int beg = blockIdx.x * EPB_F;
#pragma unroll 4
  for (int i = beg + t; i < beg + EPB_F; i += 256) {
    const int d = dst[i];
    const int b = d >> 8;
    const unsigned w = ((unsigned)src[i] << 8) | (unsigned)(d & 255);
    const int pos = atomicAdd(&lcnt[b], 1);
    binned[lbase[b] + pos] = w;
  }
}

// ---------------------------------------------------------------- per-bucket: hist -> rowptr/dinv, then csr scatter (L2-local)
__global__ __launch_bounds__(256) void k_csr(const unsigned int* __restrict__ binned,
                                             const int* __restrict__ base,
                                             int* __restrict__ rowptr,
                                             float* __restrict__ dinv,
                                             int* __restrict__ csr) {
  __shared__ int hist[BUK];
  __shared__ int sh[256];
  __shared__ int lcur[BUK];
  const int b = blockIdx.x, t = threadIdx.x;
  hist[t] = 0;
  __syncthreads();
  const int e0 = base[b * NB_F], e1 = base[(b + 1) * NB_F];
  for (int i = e0 + t; i < e1; i += 256) atomicAdd(&hist[binned[i] & 255u], 1);
  __syncthreads();
  const int hv = hist[t];
  sh[t] = hv;
  __syncthreads();
  for (int off = 1; off < 256; off <<= 1) {
    int tmp = (t >= off) ? sh[t - off] : 0;
    __syncthreads();
    sh[t] += tmp;
    __syncthreads();
  }
  const int excl = sh[t] - hv;
  lcur[t] = excl;
  const int nid = b * BUK + t;
  if (nid < NN) {
    rowptr[nid] = e0 + excl;
    dinv[nid] = rsqrtf((float)(hv + 1));
  }
  if (b == NBUK - 1 && t == 0) rowptr[NN] = e1;  // == NE
  __syncthreads();
  for (int i = e0 + t; i < e1; i += 256) {
    const unsigned w = binned[i];
    const int pos = atomicAdd(&lcur[w & 255u], 1);
    csr[e0 + pos] = (int)(w >> 8);
  }
}

// ---------------------------------------------------------------- W prep (bf16, transposed, pre-swizzled 16B chunks)
__global__ __launch_bounds__(256) void k_wprep(const float* __restrict__ W,
                                               unsigned short* __restrict__ WTs) {
  const int i = blockIdx.x * 256 + threadIdx.x;
  if (i >= INF_ * HID) return;
  const int k = i >> 7, n = i & 127;
  const int s = k >> 5, c = (k >> 3) & 3, j = k & 7;
  const int chunk = s * 512 + n * 4 + (c ^ (n & 3));
  WTs[chunk * 8 + j] = f32_to_bf16(W[i]);
}

// ---------------------------------------------------------------- MFMA GEMM: h2b = bf16( (x @ Wc) * dinv[row] )
__global__ __launch_bounds__(256) void k_gemm(const float* __restrict__ x,
                                              const unsigned short* __restrict__ WTs,
                                              const float* __restrict__ dinv,
                                              unsigned short* __restrict__ h2b) {
  __shared__ unsigned short xs[128 * 32];
  __shared__ unsigned short ws[128 * 32];
  const int tid = threadIdx.x;
  const int wave = tid >> 6, lane = tid & 63;
  const int l15 = lane & 15, l4 = lane >> 4;
  const int row0 = blockIdx.x * 128;

  f32x4 acc[2][8];
#pragma unroll
  for (int rb = 0; rb < 2; ++rb)
#pragma unroll
    for (int n = 0; n < 8; ++n) { acc[rb][n].x = 0.f; acc[rb][n].y = 0.f; acc[rb][n].z = 0.f; acc[rb][n].w = 0.f; }

  for (int s = 0; s < 8; ++s) {
#pragma unroll
    for (int p = 0; p < 2; ++p) {
      const int c = tid + p * 256;
      const int row = c >> 2, kc = c & 3;
      const int grow = row0 + row;
      unsigned short tmp[8];
      if (grow < NN) {
        const float4 v0 = *(const float4*)&x[(size_t)grow * INF_ + s * 32 + kc * 8];
        const float4 v1 = *(const float4*)&x[(size_t)grow * INF_ + s * 32 + kc * 8 + 4];
        tmp[0] = f32_to_bf16(v0.x); tmp[1] = f32_to_bf16(v0.y);
        tmp[2] = f32_to_bf16(v0.z); tmp[3] = f32_to_bf16(v0.w);
        tmp[4] = f32_to_bf16(v1.x); tmp[5] = f32_to_bf16(v1.y);
        tmp[6] = f32_to_bf16(v1.z); tmp[7] = f32_to_bf16(v1.w);
      } else {
#pragma unroll
        for (int j = 0; j < 8; ++j) tmp[j] = 0;
      }
      const int phys = kc ^ (row & 3);
      *(bf16x8*)&xs[(row * 4 + phys) * 8] = *(bf16x8*)tmp;
    }
#pragma unroll
    for (int p = 0; p < 2; ++p) {
      const int c = tid + p * 256;
      *(bf16x8*)&ws[c * 8] = *(const bf16x8*)&WTs[(s * 512 + c) * 8];
    }
    __syncthreads();
    bf16x8 af[2];
#pragma unroll
    for (int rb = 0; rb < 2; ++rb) {
      const int row = wave * 32 + rb * 16 + l15;
      af[rb] = *(const bf16x8*)&xs[(row * 4 + (l4 ^ (row & 3))) * 8];
    }
#pragma unroll
    for (int n = 0; n < 8; ++n) {
      const int col = n * 16 + l15;
      const bf16x8 bf = *(const bf16x8*)&ws[(col * 4 + (l4 ^ (col & 3))) * 8];
      acc[0][n] = __builtin_amdgcn_mfma_f32_16x16x32_bf16(af[0], bf, acc[0][n], 0, 0, 0);
      acc[1][n] = __builtin_amdgcn_mfma_f32_16x16x32_bf16(af[1], bf, acc[1][n], 0, 0, 0);
    }
    __syncthreads();
  }
#pragma unroll
  for (int rb = 0; rb < 2; ++rb) {
#pragma unroll
    for (int r = 0; r < 4; ++r) {
      const int rowg = row0 + wave * 32 + rb * 16 + l4 * 4 + r;
      if (rowg < NN) {
        const float dv = dinv[rowg];
#pragma unroll
        for (int n = 0; n < 8; ++n)
          h2b[(size_t)rowg * HID + n * 16 + l15] = f32_to_bf16(acc[rb][n][r] * dv);
      }
    }
  }
}

// ---------------------------------------------------------------- bf16 -> fp8 e4m3 neighbor cache (h8)
__global__ __launch_bounds__(256) void k_tofp8(const unsigned int* __restrict__ h2u,
                                               unsigned int* __restrict__ h8) {
  const int i = blockIdx.x * 256 + threadIdx.x;  // i < NN*HID/16 = 800000
  const uint4 a = *(const uint4*)&h2u[(size_t)i * 8];
  const uint4 b = *(const uint4*)&h2u[(size_t)i * 8 + 4];
  int w0 = 0, w1 = 0, w2 = 0, w3 = 0;
  w0 = __builtin_amdgcn_cvt_pk_fp8_f32(bf16lo_to_f32(a.x), bf16hi_to_f32(a.x), w0, false);
  w0 = __builtin_amdgcn_cvt_pk_fp8_f32(bf16lo_to_f32(a.y), bf16hi_to_f32(a.y), w0, true);
  w1 = __builtin_amdgcn_cvt_pk_fp8_f32(bf16lo_to_f32(a.z), bf16hi_to_f32(a.z), w1, false);
  w1 = __builtin_amdgcn_cvt_pk_fp8_f32(bf16lo_to_f32(a.w), bf16hi_to_f32(a.w), w1, true);
  w2 = __builtin_amdgcn_cvt_pk_fp8_f32(bf16lo_to_f32(b.x), bf16hi_to_f32(b.x), w2, false);
  w2 = __builtin_amdgcn_cvt_pk_fp8_f32(bf16lo_to_f32(b.y), bf16hi_to_f32(b.y), w2, true);
  w3 = __builtin_amdgcn_cvt_pk_fp8_f32(bf16lo_to_f32(b.z), bf16hi_to_f32(b.z), w3, false);
  w3 = __builtin_amdgcn_cvt_pk_fp8_f32(bf16lo_to_f32(b.w), bf16hi_to_f32(b.w), w3, true);
  uint4 o; o.x = (unsigned)w0; o.y = (unsigned)w1; o.z = (unsigned)w2; o.w = (unsigned)w3;
  *(uint4*)&h8[(size_t)i * 4] = o;
}

// ---------------------------------------------------------------- gather + finalize, 4 edges per VMEM instr, 4-deep MLP
// wave handles NPW consecutive nodes; lane l: m=l&15 owns channels 8m..8m+7, eg=l>>4 = edge slot
__global__ __launch_bounds__(256) void k_gather(const int* __restrict__ rowptr,
                                                const int* __restrict__ csr,
                                                const unsigned int* __restrict__ h8,
                                                const unsigned int* __restrict__ h2u,
                                                const float* __restrict__ dinv,
                                                const float* __restrict__ bc,
                                                const float* __restrict__ Wl,
                                                const float* __restrict__ bl,
                                                float* __restrict__ out) {
  const int lane = threadIdx.x & 63;
  const int m = lane & 15, eg = lane >> 4;
  const int wid = __builtin_amdgcn_readfirstlane(blockIdx.x * 4 + (threadIdx.x >> 6));
  const int v0 = wid * NPW;
  if (v0 >= NN) return;
  const int v1 = min(v0 + NPW, NN);

  // hoist Wl (rows 8m..8m+7, cols 4*eg..4*eg+3), bc (channels 8m..8m+7), bl (4*eg..)
  float4 wl[8];
#pragma unroll
  for (int r = 0; r < 8; ++r) wl[r] = *(const float4*)&Wl[(size_t)(8 * m + r) * OUTF + 4 * eg];
  const float4 bca = *(const float4*)&bc[8 * m];
  const float4 bcb = *(const float4*)&bc[8 * m + 4];
  const float4 bl4 = *(const float4*)&bl[4 * eg];
  const uint2* h8p = (const uint2*)h8;  // row r at h8p + r*16, lane's 8B at +m

  for (int v = v0; v < v1; ++v) {
    const int rp = __builtin_amdgcn_readfirstlane(rowptr[v]);
    const int re = __builtin_amdgcn_readfirstlane(rowptr[v + 1]);
    float acc[8];
#pragma unroll
    for (int q = 0; q < 8; ++q) acc[q] = 0.f;

    for (int base = rp; base < re; base += 64) {
      const int nb = min(64, re - base);
      const int csrv = (base + lane < re) ? csr[base + lane] : 0;
      int o = 0;
      // main: 16 edges per iteration -> 4 independent loads in flight
      for (; o + 16 <= nb; o += 16) {
        const int s0 = __shfl(csrv, o + eg);
        const int s1 = __shfl(csrv, o + 4 + eg);
        const int s2 = __shfl(csrv, o + 8 + eg);
        const int s3 = __shfl(csrv, o + 12 + eg);
        const uint2 u0 = h8p[(size_t)s0 * 16 + m];
        const uint2 u1 = h8p[(size_t)s1 * 16 + m];
        const uint2 u2 = h8p[(size_t)s2 * 16 + m];
        const uint2 u3 = h8p[(size_t)s3 * 16 + m];
        ACC_FP8(u0, acc);
        ACC_FP8(u1, acc);
        ACC_FP8(u2, acc);
        ACC_FP8(u3, acc);
      }
      // tail: 4 edges at a time, predicated
      for (; o < nb; o += 4) {
        const int src = __shfl(csrv, o + eg);
        if (o + eg < nb) {
          const uint2 u = h8p[(size_t)src * 16 + m];
          ACC_FP8(u, acc);
        }
      }
    }
    // cross-group reduce: lanes m, m+16, m+32, m+48 -> full sums everywhere
#pragma unroll
    for (int q = 0; q < 8; ++q) {
      acc[q] += __shfl_xor(acc[q], 16);
      acc[q] += __shfl_xor(acc[q], 32);
    }
    // self-loop (bf16) + bias + relu
    const float dv = dinv[v];
    const uint4 su = *(const uint4*)&h2u[((size_t)v << 6) + 4 * m];
    float t[8];
    t[0] = fmaxf(fmaf(dv, acc[0] + bf16lo_to_f32(su.x), bca.x), 0.f);
    t[1] = fmaxf(fmaf(dv, acc[1] + bf16hi_to_f32(su.x), bca.y), 0.f);
    t[2] = fmaxf(fmaf(dv, acc[2] + bf16lo_to_f32(su.y), bca.z), 0.f);
    t[3] = fmaxf(fmaf(dv, acc[3] + bf16hi_to_f32(su.y), bca.w), 0.f);
    t[4] = fmaxf(fmaf(dv, acc[4] + bf16lo_to_f32(su.z), bcb.x), 0.f);
    t[5] = fmaxf(fmaf(dv, acc[5] + bf16hi_to_f32(su.z), bcb.y), 0.f);
    t[6] = fmaxf(fmaf(dv, acc[6] + bf16lo_to_f32(su.w), bcb.z), 0.f);
    t[7] = fmaxf(fmaf(dv, acc[7] + bf16hi_to_f32(su.w), bcb.w), 0.f);
    // partial logits for this group's 4 outputs
    float p0 = 0.f, p1 = 0.f, p2 = 0.f, p3 = 0.f;
#pragma unroll
    for (int r = 0; r < 8; ++r) {
      p0 = fmaf(t[r], wl[r].x, p0);
      p1 = fmaf(t[r], wl[r].y, p1);
      p2 = fmaf(t[r], wl[r].z, p2);
      p3 = fmaf(t[r], wl[r].w, p3);
    }
    // reduce over the 16 lanes of the group
#pragma unroll
    for (int off = 1; off <= 8; off <<= 1) {
      p0 += __shfl_xor(p0, off);
      p1 += __shfl_xor(p1, off);
      p2 += __shfl_xor(p2, off);
      p3 += __shfl_xor(p3, off);
    }
    p0 += bl4.x; p1 += bl4.y; p2 += bl4.z; p3 += bl4.w;
    // softmax across 16 outputs (4 per group)
    float mx = fmaxf(fmaxf(p0, p1), fmaxf(p2, p3));
    mx = fmaxf(mx, __shfl_xor(mx, 16));
    mx = fmaxf(mx, __shfl_xor(mx, 32));
    float se = expf(p0 - mx) + expf(p1 - mx) + expf(p2 - mx) + expf(p3 - mx);
    se += __shfl_xor(se, 16);
    se += __shfl_xor(se, 32);
    const float lse = mx + logf(se);
    if (m == 0) {
      float4 o4;
      o4.x = p0 - lse; o4.y = p1 - lse; o4.z = p2 - lse; o4.w = p3 - lse;
      *(float4*)&out[(size_t)v * OUTF + 4 * eg] = o4;
    }
  }
}

// ---------------------------------------------------------------- launch
extern "C" void kernel_launch(void* const* d_in, const int* in_sizes, int n_in,
                              void* d_out, int out_size, void* d_ws, size_t ws_size,
                              hipStream_t stream) {
  const float* x  = (const float*)d_in[0];
  const int*   ei = (const int*)d_in[1];
  const float* Wc = (const float*)d_in[2];
  const float* bc = (const float*)d_in[3];
  const float* Wl = (const float*)d_in[4];
  const float* bl = (const float*)d_in[5];
  float* out = (float*)d_out;

  unsigned short* h2b = (unsigned short*)d_ws;            // 25.6 MB
  unsigned short* WTs = h2b + (size_t)NN * HID;           // 64 KB
  float* dinv   = (float*)(WTs + (size_t)INF_ * HID);     // NN f32
  int*   rowptr = (int*)(dinv + NN);                      // NN+1
  int*   H      = rowptr + NN + 1;                        // NB2
  int*   base   = H + NB2;                                // NB2+1
  unsigned int* binned = (unsigned int*)(base + NB2 + 1); // NE
  int*   csr    = (int*)(binned + NE);                    // NE
  unsigned int* h8 = (unsigned int*)(csr + NE);           // NN*HID fp8 = 12.8 MB

  const int* srcv = ei;
  const int* dstv = ei + NE;

  k_hist2d<<<NB_F, 256, 0, stream>>>(dstv, H);
  k_scan<<<1, SCAN_T, 0, stream>>>(H, base);
  k_fillb<<<NB_F, 256, 0, stream>>>(srcv, dstv, base, binned);
  k_csr<<<NBUK, 256, 0, stream>>>(binned, base, rowptr, dinv, csr);
  k_wprep<<<(INF_ * HID + 255) / 256, 256, 0, stream>>>(Wc, WTs);
  k_gemm<<<(NN + 127) / 128, 256, 0, stream>>>(x, WTs, dinv, h2b);
  k_tofp8<<<(NN * HID / 16 + 255) / 256, 256, 0, stream>>>((const unsigned int*)h2b, h8);
  k_gather<<<GBLK, 256, 0, stream>>>(rowptr, csr, h8, (const unsigned int*)h2b,
                                     dinv, bc, Wl, bl, out);
}